// Round 1
// baseline (1210.540 us; speedup 1.0000x reference)
//
#include <hip/hip_runtime.h>
#include <math.h>

#define NF 128
#define NC 40

// ---------------- CSR build ----------------

__global__ __launch_bounds__(256) void count_kernel(const int* __restrict__ tgt,
                                                    int* __restrict__ cnt, int e) {
  int i = blockIdx.x * 256 + threadIdx.x;
  if (i < e) atomicAdd(&cnt[tgt[i]], 1);
}

// Single-block exclusive scan over n counts. fill[] in: counts, out: row starts.
// rp[] out: row_ptr (n+1).
__global__ __launch_bounds__(1024) void scan_kernel(int* __restrict__ fill,
                                                    int* __restrict__ rp, int n) {
  __shared__ int wsum[16];
  __shared__ int carry_s;
  int tid = threadIdx.x;
  int lane = tid & 63, wid = tid >> 6;
  if (tid == 0) carry_s = 0;
  __syncthreads();
  for (int base = 0; base < n; base += 1024) {
    int i = base + tid;
    int v = (i < n) ? fill[i] : 0;
    // inclusive wave scan
    int x = v;
    #pragma unroll
    for (int off = 1; off < 64; off <<= 1) {
      int t = __shfl_up(x, off);
      if (lane >= off) x += t;
    }
    if (lane == 63) wsum[wid] = x;
    __syncthreads();
    if (wid == 0) {
      int ws = (lane < 16) ? wsum[lane] : 0;
      int y = ws;
      #pragma unroll
      for (int off = 1; off < 16; off <<= 1) {
        int t = __shfl_up(y, off);
        if (lane >= off) y += t;
      }
      if (lane < 16) wsum[lane] = y - ws;  // exclusive wave offsets
    }
    __syncthreads();
    int incl = x + wsum[wid];
    int carry = carry_s;
    int excl = carry + incl - v;
    if (i < n) { rp[i] = excl; fill[i] = excl; }
    __syncthreads();
    if (tid == 1023) carry_s = carry + incl;  // chunk total
    __syncthreads();
  }
  if (tid == 0) rp[n] = carry_s;
}

__global__ __launch_bounds__(256) void fill_kernel(const int* __restrict__ src,
                                                   const int* __restrict__ tgt,
                                                   const float* __restrict__ mw,
                                                   int* __restrict__ cursor,
                                                   int* __restrict__ cs,
                                                   float* __restrict__ cw, int e) {
  int i = blockIdx.x * 256 + threadIdx.x;
  if (i < e) {
    int t = tgt[i];
    int pos = atomicAdd(&cursor[t], 1);
    cs[pos] = src[i];
    cw[pos] = mw[i];
  }
}

// ---------------- GEMM: T[N,128] = X[N,128] @ W[128,128] ----------------
// block = 256 threads, 64 rows/block; thread = (rowgroup of 8 rows) x (4 cols)

__global__ __launch_bounds__(256) void gemm128_kernel(const float* __restrict__ X,
                                                      const float* __restrict__ W,
                                                      float* __restrict__ T, int n) {
  __shared__ float Xs[64][NF];
  int block_row = blockIdx.x * 64;
  int tid = threadIdx.x;
  #pragma unroll
  for (int it = 0; it < 8; ++it) {
    int flat = it * 1024 + tid * 4;
    int r = flat >> 7, c = flat & 127;
    int gr = block_row + r;
    float4 v = make_float4(0.f, 0.f, 0.f, 0.f);
    if (gr < n) v = *(const float4*)&X[(size_t)gr * NF + c];
    *(float4*)&Xs[r][c] = v;
  }
  __syncthreads();
  int cg = tid & 31;   // 32 col groups * 4 cols
  int rg = tid >> 5;   // 8 row groups * 8 rows
  float4 acc[8];
  #pragma unroll
  for (int r = 0; r < 8; ++r) acc[r] = make_float4(0.f, 0.f, 0.f, 0.f);
  for (int k = 0; k < NF; ++k) {
    float4 w = *(const float4*)&W[k * NF + cg * 4];
    #pragma unroll
    for (int r = 0; r < 8; ++r) {
      float xv = Xs[rg * 8 + r][k];
      acc[r].x += xv * w.x;
      acc[r].y += xv * w.y;
      acc[r].z += xv * w.z;
      acc[r].w += xv * w.w;
    }
  }
  #pragma unroll
  for (int r = 0; r < 8; ++r) {
    int gr = block_row + rg * 8 + r;
    if (gr < n) *(float4*)&T[(size_t)gr * NF + cg * 4] = acc[r];
  }
}

// ---------------- aggregation (pull), 128 feat: one wave per node ----------------

template <bool RELU, bool RES>
__global__ __launch_bounds__(256) void agg128_kernel(const float* __restrict__ T,
                                                     const int* __restrict__ rp,
                                                     const int* __restrict__ cs,
                                                     const float* __restrict__ cw,
                                                     const float* __restrict__ bias,
                                                     const float* __restrict__ Hres,
                                                     float* __restrict__ Hout, int n) {
  int node = (blockIdx.x * 256 + threadIdx.x) >> 6;
  int lane = threadIdx.x & 63;
  if (node >= n) return;
  int beg = rp[node], end = rp[node + 1];
  float ax = 0.f, ay = 0.f;
  for (int eidx = beg; eidx < end; ++eidx) {
    int s = cs[eidx];
    float w = cw[eidx];
    float2 v = *(const float2*)&T[(size_t)s * NF + lane * 2];
    ax += w * v.x;
    ay += w * v.y;
  }
  float2 b = *(const float2*)&bias[lane * 2];
  float ox = ax + b.x, oy = ay + b.y;
  if (RELU) { ox = fmaxf(ox, 0.f); oy = fmaxf(oy, 0.f); }
  if (RES) {
    float2 r = *(const float2*)&Hres[(size_t)node * NF + lane * 2];
    ox += r.x; oy += r.y;
  }
  float2 o; o.x = ox; o.y = oy;
  *(float2*)&Hout[(size_t)node * NF + lane * 2] = o;
}

// ---------------- final layer GEMM: T40[N,40] = X[N,128] @ W3[128,40] ----------------

__global__ __launch_bounds__(256) void gemm40_kernel(const float* __restrict__ X,
                                                     const float* __restrict__ W,
                                                     float* __restrict__ T, int n) {
  __shared__ float Xs[4][NF];
  int wid = threadIdx.x >> 6;
  int lane = threadIdx.x & 63;
  int node = blockIdx.x * 4 + wid;
  bool nvalid = node < n;
  if (nvalid) {
    *(float2*)&Xs[wid][lane * 2] = *(const float2*)&X[(size_t)node * NF + lane * 2];
  }
  __syncthreads();
  bool cvalid = lane < NC;
  int c = cvalid ? lane : 0;
  float acc = 0.f;
  for (int k = 0; k < NF; ++k) {
    acc += Xs[wid][k] * W[k * NC + c];
  }
  if (nvalid && cvalid) T[(size_t)node * NC + lane] = acc;
}

// ---------------- final aggregation + bias + log_softmax fused ----------------

__global__ __launch_bounds__(256) void agg40_lsm_kernel(const float* __restrict__ T,
                                                        const int* __restrict__ rp,
                                                        const int* __restrict__ cs,
                                                        const float* __restrict__ cw,
                                                        const float* __restrict__ bias,
                                                        float* __restrict__ out, int n) {
  int node = (blockIdx.x * 256 + threadIdx.x) >> 6;
  int lane = threadIdx.x & 63;
  if (node >= n) return;
  bool valid = lane < NC;
  int c = valid ? lane : 0;
  int beg = rp[node], end = rp[node + 1];
  float acc = 0.f;
  for (int eidx = beg; eidx < end; ++eidx) {
    int s = cs[eidx];
    float w = cw[eidx];
    acc += w * T[(size_t)s * NC + c];
  }
  float v = valid ? (acc + bias[lane]) : -INFINITY;
  float m = v;
  #pragma unroll
  for (int off = 32; off; off >>= 1) m = fmaxf(m, __shfl_xor(m, off));
  float ex = valid ? expf(v - m) : 0.f;
  float s = ex;
  #pragma unroll
  for (int off = 32; off; off >>= 1) s += __shfl_xor(s, off);
  if (valid) out[(size_t)node * NC + lane] = v - m - logf(s);
}

// ---------------- launch ----------------

extern "C" void kernel_launch(void* const* d_in, const int* in_sizes, int n_in,
                              void* d_out, int out_size, void* d_ws, size_t ws_size,
                              hipStream_t stream) {
  const float* x   = (const float*)d_in[0];
  const int*   src = (const int*)d_in[1];
  const int*   tgt = (const int*)d_in[2];
  const float* mw  = (const float*)d_in[3];
  const float* W0  = (const float*)d_in[4];
  const float* b0  = (const float*)d_in[5];
  const float* W1  = (const float*)d_in[6];
  const float* b1  = (const float*)d_in[7];
  const float* W2  = (const float*)d_in[8];
  const float* b2  = (const float*)d_in[9];
  const float* W3  = (const float*)d_in[10];
  const float* b3  = (const float*)d_in[11];
  int n = in_sizes[0] / NF;
  int e = in_sizes[1];
  float* out = (float*)d_out;

  char* ws = (char*)d_ws;
  size_t nb = (size_t)n * NF * sizeof(float);
  float* bufA = (float*)(ws);
  float* bufB = (float*)(ws + nb);
  float* bufT = (float*)(ws + 2 * nb);
  char* p = ws + 3 * nb;
  int* rp = (int*)p;     p += (((size_t)(n + 1) * 4) + 255) / 256 * 256;
  int* fill = (int*)p;   p += (((size_t)n * 4) + 255) / 256 * 256;
  int* cs = (int*)p;     p += (((size_t)e * 4) + 255) / 256 * 256;
  float* cw = (float*)p;

  hipMemsetAsync(fill, 0, (size_t)n * 4, stream);
  int eb = (e + 255) / 256;
  count_kernel<<<eb, 256, 0, stream>>>(tgt, fill, e);
  scan_kernel<<<1, 1024, 0, stream>>>(fill, rp, n);
  fill_kernel<<<eb, 256, 0, stream>>>(src, tgt, mw, fill, cs, cw, e);

  int gb = (n + 63) / 64;
  int ab = (n + 3) / 4;
  // L0: h = relu(agg(x@W0) + b0)
  gemm128_kernel<<<gb, 256, 0, stream>>>(x, W0, bufT, n);
  agg128_kernel<true, false><<<ab, 256, 0, stream>>>(bufT, rp, cs, cw, b0, nullptr, bufA, n);
  // L1: h = relu(agg(h@W1) + b1) + h
  gemm128_kernel<<<gb, 256, 0, stream>>>(bufA, W1, bufT, n);
  agg128_kernel<true, true><<<ab, 256, 0, stream>>>(bufT, rp, cs, cw, b1, bufA, bufB, n);
  // L2: h = relu(agg(h@W2) + b2) + h
  gemm128_kernel<<<gb, 256, 0, stream>>>(bufB, W2, bufT, n);
  agg128_kernel<true, true><<<ab, 256, 0, stream>>>(bufT, rp, cs, cw, b2, bufB, bufA, n);
  // L3: logits = agg(h@W3) + b3 ; out = log_softmax(logits)
  gemm40_kernel<<<ab, 256, 0, stream>>>(bufA, W3, bufT, n);
  agg40_lsm_kernel<<<ab, 256, 0, stream>>>(bufT, rp, cs, cw, b3, out, n);
}

// Round 2
// 846.526 us; speedup vs baseline: 1.4300x; 1.4300x over previous
//
#include <hip/hip_runtime.h>
#include <math.h>

#define NF 128
#define NC 40

typedef unsigned short bfraw;

__device__ __forceinline__ float bf2f(unsigned short h) {
  return __uint_as_float(((unsigned)h) << 16);
}
__device__ __forceinline__ unsigned short f2bf(float f) {
  unsigned u = __float_as_uint(f);
  u += 0x7fff + ((u >> 16) & 1);  // RNE
  return (unsigned short)(u >> 16);
}

// ---------------- CSR build ----------------

__global__ __launch_bounds__(256) void count_kernel(const int* __restrict__ tgt,
                                                    int* __restrict__ cnt, int e) {
  int i = blockIdx.x * 256 + threadIdx.x;
  if (i < e) atomicAdd(&cnt[tgt[i]], 1);
}

// phase 1: per-1024-block exclusive scan; excl -> rp[i], block total -> bsum[b]
__global__ __launch_bounds__(1024) void scan1_kernel(const int* __restrict__ cnt,
                                                     int* __restrict__ rp,
                                                     int* __restrict__ bsum, int n) {
  __shared__ int wsum[16];
  int tid = threadIdx.x, lane = tid & 63, wid = tid >> 6;
  int i = blockIdx.x * 1024 + tid;
  int v = (i < n) ? cnt[i] : 0;
  int x = v;
  #pragma unroll
  for (int off = 1; off < 64; off <<= 1) {
    int t = __shfl_up(x, off);
    if (lane >= off) x += t;
  }
  if (lane == 63) wsum[wid] = x;
  __syncthreads();
  if (wid == 0) {
    int ws = (lane < 16) ? wsum[lane] : 0;
    int y = ws;
    #pragma unroll
    for (int off = 1; off < 16; off <<= 1) {
      int t = __shfl_up(y, off);
      if (lane >= off) y += t;
    }
    if (lane < 16) wsum[lane] = y - ws;
  }
  __syncthreads();
  int incl = x + wsum[wid];
  if (i < n) rp[i] = incl - v;
  if (tid == 1023) bsum[blockIdx.x] = incl;
}

// phase 2: single block scans block sums (nb <= 1024); grand total -> rp_n
__global__ __launch_bounds__(1024) void scan2_kernel(int* __restrict__ bsum, int nb,
                                                     int* __restrict__ rp_n) {
  __shared__ int wsum[16];
  int tid = threadIdx.x, lane = tid & 63, wid = tid >> 6;
  int v = (tid < nb) ? bsum[tid] : 0;
  int x = v;
  #pragma unroll
  for (int off = 1; off < 64; off <<= 1) {
    int t = __shfl_up(x, off);
    if (lane >= off) x += t;
  }
  if (lane == 63) wsum[wid] = x;
  __syncthreads();
  if (wid == 0) {
    int ws = (lane < 16) ? wsum[lane] : 0;
    int y = ws;
    #pragma unroll
    for (int off = 1; off < 16; off <<= 1) {
      int t = __shfl_up(y, off);
      if (lane >= off) y += t;
    }
    if (lane < 16) wsum[lane] = y - ws;
  }
  __syncthreads();
  int incl = x + wsum[wid];
  if (tid < nb) bsum[tid] = incl - v;
  if (tid == 1023) *rp_n = incl;
}

// phase 3: add block offsets; also init cursor
__global__ __launch_bounds__(256) void scan3_kernel(int* __restrict__ rp,
                                                    int* __restrict__ cursor,
                                                    const int* __restrict__ bsum, int n) {
  int i = blockIdx.x * 256 + threadIdx.x;
  if (i < n) {
    int v = rp[i] + bsum[i >> 10];
    rp[i] = v;
    cursor[i] = v;
  }
}

__global__ __launch_bounds__(256) void fill_kernel(const int* __restrict__ src,
                                                   const int* __restrict__ tgt,
                                                   const float* __restrict__ mw,
                                                   int* __restrict__ cursor,
                                                   int* __restrict__ cs,
                                                   float* __restrict__ cw, int e) {
  int i = blockIdx.x * 256 + threadIdx.x;
  if (i < e) {
    int t = tgt[i];
    int pos = atomicAdd(&cursor[t], 1);
    cs[pos] = src[i];
    cw[pos] = mw[i];
  }
}

// ---------------- GEMM: Tb[N,128](bf16) = X[N,128] @ W[128,128] ----------------

__global__ __launch_bounds__(256) void gemm128_kernel(const float* __restrict__ X,
                                                      const float* __restrict__ W,
                                                      bfraw* __restrict__ Tb, int n) {
  __shared__ float Xs[64][NF];
  int block_row = blockIdx.x * 64;
  int tid = threadIdx.x;
  #pragma unroll
  for (int it = 0; it < 8; ++it) {
    int flat = it * 1024 + tid * 4;
    int r = flat >> 7, c = flat & 127;
    int gr = block_row + r;
    float4 v = make_float4(0.f, 0.f, 0.f, 0.f);
    if (gr < n) v = *(const float4*)&X[(size_t)gr * NF + c];
    *(float4*)&Xs[r][c] = v;
  }
  __syncthreads();
  int cg = tid & 31;
  int rg = tid >> 5;
  float4 acc[8];
  #pragma unroll
  for (int r = 0; r < 8; ++r) acc[r] = make_float4(0.f, 0.f, 0.f, 0.f);
  for (int k = 0; k < NF; ++k) {
    float4 w = *(const float4*)&W[k * NF + cg * 4];
    #pragma unroll
    for (int r = 0; r < 8; ++r) {
      float xv = Xs[rg * 8 + r][k];
      acc[r].x += xv * w.x;
      acc[r].y += xv * w.y;
      acc[r].z += xv * w.z;
      acc[r].w += xv * w.w;
    }
  }
  #pragma unroll
  for (int r = 0; r < 8; ++r) {
    int gr = block_row + rg * 8 + r;
    if (gr < n) {
      ushort4 o;
      o.x = f2bf(acc[r].x); o.y = f2bf(acc[r].y);
      o.z = f2bf(acc[r].z); o.w = f2bf(acc[r].w);
      *(ushort4*)&Tb[(size_t)gr * NF + cg * 4] = o;
    }
  }
}

// ---------------- aggregation (pull), bf16 gather, 2 edge streams/wave ----------------

template <bool RELU, bool RES>
__global__ __launch_bounds__(256) void agg128_kernel(const bfraw* __restrict__ Tb,
                                                     const int* __restrict__ rp,
                                                     const int* __restrict__ cs,
                                                     const float* __restrict__ cw,
                                                     const float* __restrict__ bias,
                                                     const float* __restrict__ Hres,
                                                     float* __restrict__ Hout, int n) {
  int node = (blockIdx.x * 256 + threadIdx.x) >> 6;
  int lane = threadIdx.x & 63;
  if (node >= n) return;
  int half = lane >> 5;  // edge-stream id
  int fl = lane & 31;    // features 4*fl .. 4*fl+3
  int beg = rp[node], end = rp[node + 1];
  float a0 = 0.f, a1 = 0.f, a2 = 0.f, a3 = 0.f;
  int eidx = beg + half;
  for (; eidx + 2 < end; eidx += 4) {
    int s0 = cs[eidx];     float w0 = cw[eidx];
    int s1 = cs[eidx + 2]; float w1 = cw[eidx + 2];
    ushort4 v0 = *(const ushort4*)&Tb[(size_t)s0 * NF + fl * 4];
    ushort4 v1 = *(const ushort4*)&Tb[(size_t)s1 * NF + fl * 4];
    a0 = fmaf(w0, bf2f(v0.x), a0); a1 = fmaf(w0, bf2f(v0.y), a1);
    a2 = fmaf(w0, bf2f(v0.z), a2); a3 = fmaf(w0, bf2f(v0.w), a3);
    a0 = fmaf(w1, bf2f(v1.x), a0); a1 = fmaf(w1, bf2f(v1.y), a1);
    a2 = fmaf(w1, bf2f(v1.z), a2); a3 = fmaf(w1, bf2f(v1.w), a3);
  }
  if (eidx < end) {
    int s0 = cs[eidx]; float w0 = cw[eidx];
    ushort4 v0 = *(const ushort4*)&Tb[(size_t)s0 * NF + fl * 4];
    a0 = fmaf(w0, bf2f(v0.x), a0); a1 = fmaf(w0, bf2f(v0.y), a1);
    a2 = fmaf(w0, bf2f(v0.z), a2); a3 = fmaf(w0, bf2f(v0.w), a3);
  }
  a0 += __shfl_xor(a0, 32);
  a1 += __shfl_xor(a1, 32);
  a2 += __shfl_xor(a2, 32);
  a3 += __shfl_xor(a3, 32);
  if (half == 0) {
    float4 b = *(const float4*)&bias[fl * 4];
    float o0 = a0 + b.x, o1 = a1 + b.y, o2 = a2 + b.z, o3 = a3 + b.w;
    if (RELU) {
      o0 = fmaxf(o0, 0.f); o1 = fmaxf(o1, 0.f);
      o2 = fmaxf(o2, 0.f); o3 = fmaxf(o3, 0.f);
    }
    if (RES) {
      float4 r = *(const float4*)&Hres[(size_t)node * NF + fl * 4];
      o0 += r.x; o1 += r.y; o2 += r.z; o3 += r.w;
    }
    float4 o; o.x = o0; o.y = o1; o.z = o2; o.w = o3;
    *(float4*)&Hout[(size_t)node * NF + fl * 4] = o;
  }
}

// ---------------- final layer GEMM: T40[N,40] = X[N,128] @ W3[128,40] ----------------

__global__ __launch_bounds__(256) void gemm40_kernel(const float* __restrict__ X,
                                                     const float* __restrict__ W,
                                                     float* __restrict__ T, int n) {
  __shared__ float Xs[4][NF];
  int wid = threadIdx.x >> 6;
  int lane = threadIdx.x & 63;
  int node = blockIdx.x * 4 + wid;
  bool nvalid = node < n;
  if (nvalid) {
    *(float2*)&Xs[wid][lane * 2] = *(const float2*)&X[(size_t)node * NF + lane * 2];
  }
  __syncthreads();
  bool cvalid = lane < NC;
  int c = cvalid ? lane : 0;
  float acc = 0.f;
  for (int k = 0; k < NF; ++k) {
    acc += Xs[wid][k] * W[k * NC + c];
  }
  if (nvalid && cvalid) T[(size_t)node * NC + lane] = acc;
}

// ---------------- final aggregation + bias + log_softmax fused ----------------

__global__ __launch_bounds__(256) void agg40_lsm_kernel(const float* __restrict__ T,
                                                        const int* __restrict__ rp,
                                                        const int* __restrict__ cs,
                                                        const float* __restrict__ cw,
                                                        const float* __restrict__ bias,
                                                        float* __restrict__ out, int n) {
  int node = (blockIdx.x * 256 + threadIdx.x) >> 6;
  int lane = threadIdx.x & 63;
  if (node >= n) return;
  bool valid = lane < NC;
  int c = valid ? lane : 0;
  int beg = rp[node], end = rp[node + 1];
  float acc = 0.f;
  for (int eidx = beg; eidx < end; ++eidx) {
    int s = cs[eidx];
    float w = cw[eidx];
    acc += w * T[(size_t)s * NC + c];
  }
  float v = valid ? (acc + bias[lane]) : -INFINITY;
  float m = v;
  #pragma unroll
  for (int off = 32; off; off >>= 1) m = fmaxf(m, __shfl_xor(m, off));
  float ex = valid ? expf(v - m) : 0.f;
  float s = ex;
  #pragma unroll
  for (int off = 32; off; off >>= 1) s += __shfl_xor(s, off);
  if (valid) out[(size_t)node * NC + lane] = v - m - logf(s);
}

// ---------------- launch ----------------

extern "C" void kernel_launch(void* const* d_in, const int* in_sizes, int n_in,
                              void* d_out, int out_size, void* d_ws, size_t ws_size,
                              hipStream_t stream) {
  const float* x   = (const float*)d_in[0];
  const int*   src = (const int*)d_in[1];
  const int*   tgt = (const int*)d_in[2];
  const float* mw  = (const float*)d_in[3];
  const float* W0  = (const float*)d_in[4];
  const float* b0  = (const float*)d_in[5];
  const float* W1  = (const float*)d_in[6];
  const float* b1  = (const float*)d_in[7];
  const float* W2  = (const float*)d_in[8];
  const float* b2  = (const float*)d_in[9];
  const float* W3  = (const float*)d_in[10];
  const float* b3  = (const float*)d_in[11];
  int n = in_sizes[0] / NF;
  int e = in_sizes[1];
  float* out = (float*)d_out;

  char* ws = (char*)d_ws;
  size_t nbF = (size_t)n * NF * sizeof(float);          // fp32 [N,128]
  size_t nbB = ((size_t)n * NF * sizeof(bfraw) + 255) / 256 * 256;  // bf16 [N,128]
  float* bufA = (float*)(ws);
  float* bufB = (float*)(ws + nbF);
  bfraw* bufT = (bfraw*)(ws + 2 * nbF);
  float* bufT40 = (float*)(ws + 2 * nbF + nbB);
  char* p = ws + 2 * nbF + nbB + (((size_t)n * NC * sizeof(float) + 255) / 256 * 256);
  int* rp = (int*)p;     p += (((size_t)(n + 1) * 4) + 255) / 256 * 256;
  int* fill = (int*)p;   p += (((size_t)n * 4) + 255) / 256 * 256;
  int* bsum = (int*)p;   p += 4096;
  int* cs = (int*)p;     p += (((size_t)e * 4) + 255) / 256 * 256;
  float* cw = (float*)p;

  hipMemsetAsync(fill, 0, (size_t)n * 4, stream);
  int eb = (e + 255) / 256;
  int nb1 = (n + 1023) / 1024;
  count_kernel<<<eb, 256, 0, stream>>>(tgt, fill, e);
  scan1_kernel<<<nb1, 1024, 0, stream>>>(fill, rp, bsum, n);
  scan2_kernel<<<1, 1024, 0, stream>>>(bsum, nb1, &rp[n]);
  scan3_kernel<<<(n + 255) / 256, 256, 0, stream>>>(rp, fill, bsum, n);
  fill_kernel<<<eb, 256, 0, stream>>>(src, tgt, mw, fill, cs, cw, e);

  int gb = (n + 63) / 64;
  int ab = (n + 3) / 4;
  // L0: h = relu(agg(x@W0) + b0)
  gemm128_kernel<<<gb, 256, 0, stream>>>(x, W0, bufT, n);
  agg128_kernel<true, false><<<ab, 256, 0, stream>>>(bufT, rp, cs, cw, b0, nullptr, bufA, n);
  // L1: h = relu(agg(h@W1) + b1) + h
  gemm128_kernel<<<gb, 256, 0, stream>>>(bufA, W1, bufT, n);
  agg128_kernel<true, true><<<ab, 256, 0, stream>>>(bufT, rp, cs, cw, b1, bufA, bufB, n);
  // L2: h = relu(agg(h@W2) + b2) + h
  gemm128_kernel<<<gb, 256, 0, stream>>>(bufB, W2, bufT, n);
  agg128_kernel<true, true><<<ab, 256, 0, stream>>>(bufT, rp, cs, cw, b2, bufB, bufA, n);
  // L3: logits = agg(h@W3) + b3 ; out = log_softmax(logits)
  gemm40_kernel<<<ab, 256, 0, stream>>>(bufA, W3, bufT40, n);
  agg40_lsm_kernel<<<ab, 256, 0, stream>>>(bufT40, rp, cs, cw, b3, out, n);
}

// Round 3
// 718.245 us; speedup vs baseline: 1.6854x; 1.1786x over previous
//
#include <hip/hip_runtime.h>
#include <math.h>

#define NF 128
#define NC 40

typedef unsigned short bfraw;

__device__ __forceinline__ float bfLo(unsigned u) {
  return __uint_as_float(u << 16);
}
__device__ __forceinline__ float bfHi(unsigned u) {
  return __uint_as_float(u & 0xffff0000u);
}
__device__ __forceinline__ unsigned short f2bf(float f) {
  unsigned u = __float_as_uint(f);
  u += 0x7fff + ((u >> 16) & 1);  // RNE
  return (unsigned short)(u >> 16);
}

// ---------------- CSR build ----------------

__global__ __launch_bounds__(256) void count_kernel(const int* __restrict__ tgt,
                                                    int* __restrict__ cnt, int e) {
  int i = blockIdx.x * 256 + threadIdx.x;
  if (i < e) atomicAdd(&cnt[tgt[i]], 1);
}

__global__ __launch_bounds__(1024) void scan1_kernel(const int* __restrict__ cnt,
                                                     int* __restrict__ rp,
                                                     int* __restrict__ bsum, int n) {
  __shared__ int wsum[16];
  int tid = threadIdx.x, lane = tid & 63, wid = tid >> 6;
  int i = blockIdx.x * 1024 + tid;
  int v = (i < n) ? cnt[i] : 0;
  int x = v;
  #pragma unroll
  for (int off = 1; off < 64; off <<= 1) {
    int t = __shfl_up(x, off);
    if (lane >= off) x += t;
  }
  if (lane == 63) wsum[wid] = x;
  __syncthreads();
  if (wid == 0) {
    int ws = (lane < 16) ? wsum[lane] : 0;
    int y = ws;
    #pragma unroll
    for (int off = 1; off < 16; off <<= 1) {
      int t = __shfl_up(y, off);
      if (lane >= off) y += t;
    }
    if (lane < 16) wsum[lane] = y - ws;
  }
  __syncthreads();
  int incl = x + wsum[wid];
  if (i < n) rp[i] = incl - v;
  if (tid == 1023) bsum[blockIdx.x] = incl;
}

__global__ __launch_bounds__(1024) void scan2_kernel(int* __restrict__ bsum, int nb,
                                                     int* __restrict__ rp_n) {
  __shared__ int wsum[16];
  int tid = threadIdx.x, lane = tid & 63, wid = tid >> 6;
  int v = (tid < nb) ? bsum[tid] : 0;
  int x = v;
  #pragma unroll
  for (int off = 1; off < 64; off <<= 1) {
    int t = __shfl_up(x, off);
    if (lane >= off) x += t;
  }
  if (lane == 63) wsum[wid] = x;
  __syncthreads();
  if (wid == 0) {
    int ws = (lane < 16) ? wsum[lane] : 0;
    int y = ws;
    #pragma unroll
    for (int off = 1; off < 16; off <<= 1) {
      int t = __shfl_up(y, off);
      if (lane >= off) y += t;
    }
    if (lane < 16) wsum[lane] = y - ws;
  }
  __syncthreads();
  int incl = x + wsum[wid];
  if (tid < nb) bsum[tid] = incl - v;
  if (tid == 1023) *rp_n = incl;
}

__global__ __launch_bounds__(256) void scan3_kernel(int* __restrict__ rp,
                                                    int* __restrict__ cursor,
                                                    const int* __restrict__ bsum, int n) {
  int i = blockIdx.x * 256 + threadIdx.x;
  if (i < n) {
    int v = rp[i] + bsum[i >> 10];
    rp[i] = v;
    cursor[i] = v;
  }
}

__global__ __launch_bounds__(256) void fill_kernel(const int* __restrict__ src,
                                                   const int* __restrict__ tgt,
                                                   const float* __restrict__ mw,
                                                   int* __restrict__ cursor,
                                                   int* __restrict__ cs,
                                                   float* __restrict__ cw, int e) {
  int i = blockIdx.x * 256 + threadIdx.x;
  if (i < e) {
    int t = tgt[i];
    int pos = atomicAdd(&cursor[t], 1);
    cs[pos] = src[i];
    cw[pos] = mw[i];
  }
}

// ---------------- GEMM: Tb[N,128](bf16) = X[N,128] @ W[128,128] ----------------

__global__ __launch_bounds__(256) void gemm128_kernel(const float* __restrict__ X,
                                                      const float* __restrict__ W,
                                                      bfraw* __restrict__ Tb, int n) {
  __shared__ float Xs[64][NF];
  int block_row = blockIdx.x * 64;
  int tid = threadIdx.x;
  #pragma unroll
  for (int it = 0; it < 8; ++it) {
    int flat = it * 1024 + tid * 4;
    int r = flat >> 7, c = flat & 127;
    int gr = block_row + r;
    float4 v = make_float4(0.f, 0.f, 0.f, 0.f);
    if (gr < n) v = *(const float4*)&X[(size_t)gr * NF + c];
    *(float4*)&Xs[r][c] = v;
  }
  __syncthreads();
  int cg = tid & 31;
  int rg = tid >> 5;
  float4 acc[8];
  #pragma unroll
  for (int r = 0; r < 8; ++r) acc[r] = make_float4(0.f, 0.f, 0.f, 0.f);
  for (int k = 0; k < NF; ++k) {
    float4 w = *(const float4*)&W[k * NF + cg * 4];
    #pragma unroll
    for (int r = 0; r < 8; ++r) {
      float xv = Xs[rg * 8 + r][k];
      acc[r].x += xv * w.x;
      acc[r].y += xv * w.y;
      acc[r].z += xv * w.z;
      acc[r].w += xv * w.w;
    }
  }
  #pragma unroll
  for (int r = 0; r < 8; ++r) {
    int gr = block_row + rg * 8 + r;
    if (gr < n) {
      ushort4 o;
      o.x = f2bf(acc[r].x); o.y = f2bf(acc[r].y);
      o.z = f2bf(acc[r].z); o.w = f2bf(acc[r].w);
      *(ushort4*)&Tb[(size_t)gr * NF + cg * 4] = o;
    }
  }
}

// ---------------- aggregation (pull), bf16 gather ----------------
// one wave per node; 4 edge streams x 16 lanes; each lane owns 8 features (16B)

template <bool RELU, bool RES, bool BIAS, bool OUTBF>
__global__ __launch_bounds__(256) void agg128_kernel(const bfraw* __restrict__ Tb,
                                                     const int* __restrict__ rp,
                                                     const int* __restrict__ cs,
                                                     const float* __restrict__ cw,
                                                     const float* __restrict__ bias,
                                                     const float* __restrict__ Hres,
                                                     void* __restrict__ HoutV, int n) {
  int node = (blockIdx.x * 256 + threadIdx.x) >> 6;
  int lane = threadIdx.x & 63;
  if (node >= n) return;
  int st = lane >> 4;  // edge-stream 0..3
  int fl = lane & 15;  // features 8*fl .. 8*fl+7
  int beg = rp[node], end = rp[node + 1];
  float a[8];
  #pragma unroll
  for (int i = 0; i < 8; ++i) a[i] = 0.f;
  int eidx = beg + st;
  for (; eidx + 4 < end; eidx += 8) {
    int s0 = cs[eidx];     float w0 = cw[eidx];
    int s1 = cs[eidx + 4]; float w1 = cw[eidx + 4];
    uint4 q0 = *(const uint4*)&Tb[(size_t)s0 * NF + fl * 8];
    uint4 q1 = *(const uint4*)&Tb[(size_t)s1 * NF + fl * 8];
    a[0] = fmaf(w0, bfLo(q0.x), a[0]); a[1] = fmaf(w0, bfHi(q0.x), a[1]);
    a[2] = fmaf(w0, bfLo(q0.y), a[2]); a[3] = fmaf(w0, bfHi(q0.y), a[3]);
    a[4] = fmaf(w0, bfLo(q0.z), a[4]); a[5] = fmaf(w0, bfHi(q0.z), a[5]);
    a[6] = fmaf(w0, bfLo(q0.w), a[6]); a[7] = fmaf(w0, bfHi(q0.w), a[7]);
    a[0] = fmaf(w1, bfLo(q1.x), a[0]); a[1] = fmaf(w1, bfHi(q1.x), a[1]);
    a[2] = fmaf(w1, bfLo(q1.y), a[2]); a[3] = fmaf(w1, bfHi(q1.y), a[3]);
    a[4] = fmaf(w1, bfLo(q1.z), a[4]); a[5] = fmaf(w1, bfHi(q1.z), a[5]);
    a[6] = fmaf(w1, bfLo(q1.w), a[6]); a[7] = fmaf(w1, bfHi(q1.w), a[7]);
  }
  if (eidx < end) {
    int s0 = cs[eidx]; float w0 = cw[eidx];
    uint4 q0 = *(const uint4*)&Tb[(size_t)s0 * NF + fl * 8];
    a[0] = fmaf(w0, bfLo(q0.x), a[0]); a[1] = fmaf(w0, bfHi(q0.x), a[1]);
    a[2] = fmaf(w0, bfLo(q0.y), a[2]); a[3] = fmaf(w0, bfHi(q0.y), a[3]);
    a[4] = fmaf(w0, bfLo(q0.z), a[4]); a[5] = fmaf(w0, bfHi(q0.z), a[5]);
    a[6] = fmaf(w0, bfLo(q0.w), a[6]); a[7] = fmaf(w0, bfHi(q0.w), a[7]);
  }
  #pragma unroll
  for (int i = 0; i < 8; ++i) {
    a[i] += __shfl_xor(a[i], 16);
    a[i] += __shfl_xor(a[i], 32);
  }
  if (st == 0) {
    if (BIAS) {
      float4 b0 = *(const float4*)&bias[fl * 8];
      float4 b1 = *(const float4*)&bias[fl * 8 + 4];
      a[0] += b0.x; a[1] += b0.y; a[2] += b0.z; a[3] += b0.w;
      a[4] += b1.x; a[5] += b1.y; a[6] += b1.z; a[7] += b1.w;
    }
    if (RELU) {
      #pragma unroll
      for (int i = 0; i < 8; ++i) a[i] = fmaxf(a[i], 0.f);
    }
    if (RES) {
      float4 r0 = *(const float4*)&Hres[(size_t)node * NF + fl * 8];
      float4 r1 = *(const float4*)&Hres[(size_t)node * NF + fl * 8 + 4];
      a[0] += r0.x; a[1] += r0.y; a[2] += r0.z; a[3] += r0.w;
      a[4] += r1.x; a[5] += r1.y; a[6] += r1.z; a[7] += r1.w;
    }
    if (OUTBF) {
      bfraw* Hout = (bfraw*)HoutV;
      uint4 o;
      o.x = ((unsigned)f2bf(a[1]) << 16) | f2bf(a[0]);
      o.y = ((unsigned)f2bf(a[3]) << 16) | f2bf(a[2]);
      o.z = ((unsigned)f2bf(a[5]) << 16) | f2bf(a[4]);
      o.w = ((unsigned)f2bf(a[7]) << 16) | f2bf(a[6]);
      *(uint4*)&Hout[(size_t)node * NF + fl * 8] = o;
    } else {
      float* Hout = (float*)HoutV;
      float4 o0, o1;
      o0.x = a[0]; o0.y = a[1]; o0.z = a[2]; o0.w = a[3];
      o1.x = a[4]; o1.y = a[5]; o1.z = a[6]; o1.w = a[7];
      *(float4*)&Hout[(size_t)node * NF + fl * 8] = o0;
      *(float4*)&Hout[(size_t)node * NF + fl * 8 + 4] = o1;
    }
  }
}

// ---------------- fused final: logits = A@W3 + b3 ; out = log_softmax ----------------

__global__ __launch_bounds__(256) void gemm40_lsm_kernel(const float* __restrict__ A,
                                                         const float* __restrict__ W,
                                                         const float* __restrict__ bias,
                                                         float* __restrict__ out, int n) {
  __shared__ float Xs[4][NF];
  int wid = threadIdx.x >> 6;
  int lane = threadIdx.x & 63;
  int node = blockIdx.x * 4 + wid;
  if (node < n) {
    *(float2*)&Xs[wid][lane * 2] = *(const float2*)&A[(size_t)node * NF + lane * 2];
  }
  __syncthreads();
  if (node >= n) return;
  bool valid = lane < NC;
  int c = valid ? lane : 0;
  float acc0 = 0.f, acc1 = 0.f, acc2 = 0.f, acc3 = 0.f;
  #pragma unroll 4
  for (int k = 0; k < NF; k += 4) {
    acc0 = fmaf(Xs[wid][k],     W[(k)     * NC + c], acc0);
    acc1 = fmaf(Xs[wid][k + 1], W[(k + 1) * NC + c], acc1);
    acc2 = fmaf(Xs[wid][k + 2], W[(k + 2) * NC + c], acc2);
    acc3 = fmaf(Xs[wid][k + 3], W[(k + 3) * NC + c], acc3);
  }
  float v = valid ? (acc0 + acc1 + acc2 + acc3 + bias[lane]) : -INFINITY;
  float m = v;
  #pragma unroll
  for (int off = 32; off; off >>= 1) m = fmaxf(m, __shfl_xor(m, off));
  float ex = valid ? expf(v - m) : 0.f;
  float s = ex;
  #pragma unroll
  for (int off = 32; off; off >>= 1) s += __shfl_xor(s, off);
  if (valid) out[(size_t)node * NC + lane] = v - m - logf(s);
}

// ---------------- launch ----------------

extern "C" void kernel_launch(void* const* d_in, const int* in_sizes, int n_in,
                              void* d_out, int out_size, void* d_ws, size_t ws_size,
                              hipStream_t stream) {
  const float* x   = (const float*)d_in[0];
  const int*   src = (const int*)d_in[1];
  const int*   tgt = (const int*)d_in[2];
  const float* mw  = (const float*)d_in[3];
  const float* W0  = (const float*)d_in[4];
  const float* b0  = (const float*)d_in[5];
  const float* W1  = (const float*)d_in[6];
  const float* b1  = (const float*)d_in[7];
  const float* W2  = (const float*)d_in[8];
  const float* b2  = (const float*)d_in[9];
  const float* W3  = (const float*)d_in[10];
  const float* b3  = (const float*)d_in[11];
  int n = in_sizes[0] / NF;
  int e = in_sizes[1];
  float* out = (float*)d_out;

  char* ws = (char*)d_ws;
  size_t nbF = (size_t)n * NF * sizeof(float);                       // fp32 [N,128]
  size_t nbB = ((size_t)n * NF * sizeof(bfraw) + 255) / 256 * 256;   // bf16 [N,128]
  float* bufA = (float*)(ws);                 // h0 / h1-alt / A
  float* bufB = (float*)(ws + nbF);           // h1
  bfraw* bufT = (bfraw*)(ws + 2 * nbF);       // per-layer transform out (bf16)
  bfraw* bufC = (bfraw*)(ws + 2 * nbF + nbB); // h2 (bf16)
  char* p = ws + 2 * nbF + 2 * nbB;
  int* rp = (int*)p;     p += (((size_t)(n + 1) * 4) + 255) / 256 * 256;
  int* fill = (int*)p;   p += (((size_t)n * 4) + 255) / 256 * 256;
  int* bsum = (int*)p;   p += 4096;
  int* cs = (int*)p;     p += (((size_t)e * 4) + 255) / 256 * 256;
  float* cw = (float*)p;

  hipMemsetAsync(fill, 0, (size_t)n * 4, stream);
  int eb = (e + 255) / 256;
  int nb1 = (n + 1023) / 1024;
  count_kernel<<<eb, 256, 0, stream>>>(tgt, fill, e);
  scan1_kernel<<<nb1, 1024, 0, stream>>>(fill, rp, bsum, n);
  scan2_kernel<<<1, 1024, 0, stream>>>(bsum, nb1, &rp[n]);
  scan3_kernel<<<(n + 255) / 256, 256, 0, stream>>>(rp, fill, bsum, n);
  fill_kernel<<<eb, 256, 0, stream>>>(src, tgt, mw, fill, cs, cw, e);

  int gb = (n + 63) / 64;
  int ab = (n + 3) / 4;
  // L0: h0 = relu(agg(x@W0) + b0)
  gemm128_kernel<<<gb, 256, 0, stream>>>(x, W0, bufT, n);
  agg128_kernel<true, false, true, false><<<ab, 256, 0, stream>>>(
      bufT, rp, cs, cw, b0, nullptr, bufA, n);
  // L1: h1 = relu(agg(h0@W1) + b1) + h0
  gemm128_kernel<<<gb, 256, 0, stream>>>(bufA, W1, bufT, n);
  agg128_kernel<true, true, true, false><<<ab, 256, 0, stream>>>(
      bufT, rp, cs, cw, b1, bufA, bufB, n);
  // L2: h2 = relu(agg(h1@W2) + b2) + h1   (stored bf16)
  gemm128_kernel<<<gb, 256, 0, stream>>>(bufB, W2, bufT, n);
  agg128_kernel<true, true, true, true><<<ab, 256, 0, stream>>>(
      bufT, rp, cs, cw, b2, bufB, bufC, n);
  // Final: A = agg(h2) ; out = log_softmax(A@W3 + b3)
  agg128_kernel<false, false, false, false><<<ab, 256, 0, stream>>>(
      bufC, rp, cs, cw, nullptr, nullptr, bufA, n);
  gemm40_lsm_kernel<<<ab, 256, 0, stream>>>(bufA, W3, b3, out, n);
}

// Round 4
// 639.133 us; speedup vs baseline: 1.8940x; 1.1238x over previous
//
#include <hip/hip_runtime.h>
#include <math.h>

#define NF 128
#define NC 40

typedef unsigned short bfraw;

__device__ __forceinline__ float bfLo(unsigned u) {
  return __uint_as_float(u << 16);
}
__device__ __forceinline__ float bfHi(unsigned u) {
  return __uint_as_float(u & 0xffff0000u);
}
__device__ __forceinline__ unsigned short f2bf(float f) {
  unsigned u = __float_as_uint(f);
  u += 0x7fff + ((u >> 16) & 1);  // RNE
  return (unsigned short)(u >> 16);
}

// ---------------- CSR build ----------------

__global__ __launch_bounds__(256) void count_kernel(const int* __restrict__ tgt,
                                                    int* __restrict__ cnt, int e) {
  int i = blockIdx.x * 256 + threadIdx.x;
  if (i < e) atomicAdd(&cnt[tgt[i]], 1);
}

__global__ __launch_bounds__(1024) void scan1_kernel(const int* __restrict__ cnt,
                                                     int* __restrict__ rp,
                                                     int* __restrict__ bsum, int n) {
  __shared__ int wsum[16];
  int tid = threadIdx.x, lane = tid & 63, wid = tid >> 6;
  int i = blockIdx.x * 1024 + tid;
  int v = (i < n) ? cnt[i] : 0;
  int x = v;
  #pragma unroll
  for (int off = 1; off < 64; off <<= 1) {
    int t = __shfl_up(x, off);
    if (lane >= off) x += t;
  }
  if (lane == 63) wsum[wid] = x;
  __syncthreads();
  if (wid == 0) {
    int ws = (lane < 16) ? wsum[lane] : 0;
    int y = ws;
    #pragma unroll
    for (int off = 1; off < 16; off <<= 1) {
      int t = __shfl_up(y, off);
      if (lane >= off) y += t;
    }
    if (lane < 16) wsum[lane] = y - ws;
  }
  __syncthreads();
  int incl = x + wsum[wid];
  if (i < n) rp[i] = incl - v;
  if (tid == 1023) bsum[blockIdx.x] = incl;
}

__global__ __launch_bounds__(1024) void scan2_kernel(int* __restrict__ bsum, int nb,
                                                     int* __restrict__ rp_n) {
  __shared__ int wsum[16];
  int tid = threadIdx.x, lane = tid & 63, wid = tid >> 6;
  int v = (tid < nb) ? bsum[tid] : 0;
  int x = v;
  #pragma unroll
  for (int off = 1; off < 64; off <<= 1) {
    int t = __shfl_up(x, off);
    if (lane >= off) x += t;
  }
  if (lane == 63) wsum[wid] = x;
  __syncthreads();
  if (wid == 0) {
    int ws = (lane < 16) ? wsum[lane] : 0;
    int y = ws;
    #pragma unroll
    for (int off = 1; off < 16; off <<= 1) {
      int t = __shfl_up(y, off);
      if (lane >= off) y += t;
    }
    if (lane < 16) wsum[lane] = y - ws;
  }
  __syncthreads();
  int incl = x + wsum[wid];
  if (tid < nb) bsum[tid] = incl - v;
  if (tid == 1023) *rp_n = incl;
}

__global__ __launch_bounds__(256) void scan3_kernel(int* __restrict__ rp,
                                                    int* __restrict__ cursor,
                                                    const int* __restrict__ bsum, int n) {
  int i = blockIdx.x * 256 + threadIdx.x;
  if (i < n) {
    int v = rp[i] + bsum[i >> 10];
    rp[i] = v;
    cursor[i] = v;
  }
}

// packed edge record: {src, weight_bits} — one 8B store instead of two 4B scatters
__global__ __launch_bounds__(256) void fill_kernel(const int* __restrict__ src,
                                                   const int* __restrict__ tgt,
                                                   const float* __restrict__ mw,
                                                   int* __restrict__ cursor,
                                                   int2* __restrict__ ecsr, int e) {
  int i = blockIdx.x * 256 + threadIdx.x;
  if (i < e) {
    int t = tgt[i];
    int pos = atomicAdd(&cursor[t], 1);
    ecsr[pos] = make_int2(src[i], __float_as_int(mw[i]));
  }
}

// ---------------- GEMM: Tb[N,128](bf16) = X[N,128] @ W[128,128] ----------------

__global__ __launch_bounds__(256) void gemm128_kernel(const float* __restrict__ X,
                                                      const float* __restrict__ W,
                                                      bfraw* __restrict__ Tb, int n) {
  __shared__ float Xs[64][NF];
  int block_row = blockIdx.x * 64;
  int tid = threadIdx.x;
  #pragma unroll
  for (int it = 0; it < 8; ++it) {
    int flat = it * 1024 + tid * 4;
    int r = flat >> 7, c = flat & 127;
    int gr = block_row + r;
    float4 v = make_float4(0.f, 0.f, 0.f, 0.f);
    if (gr < n) v = *(const float4*)&X[(size_t)gr * NF + c];
    *(float4*)&Xs[r][c] = v;
  }
  __syncthreads();
  int cg = tid & 31;
  int rg = tid >> 5;
  float4 acc[8];
  #pragma unroll
  for (int r = 0; r < 8; ++r) acc[r] = make_float4(0.f, 0.f, 0.f, 0.f);
  for (int k = 0; k < NF; ++k) {
    float4 w = *(const float4*)&W[k * NF + cg * 4];
    #pragma unroll
    for (int r = 0; r < 8; ++r) {
      float xv = Xs[rg * 8 + r][k];
      acc[r].x += xv * w.x;
      acc[r].y += xv * w.y;
      acc[r].z += xv * w.z;
      acc[r].w += xv * w.w;
    }
  }
  #pragma unroll
  for (int r = 0; r < 8; ++r) {
    int gr = block_row + rg * 8 + r;
    if (gr < n) {
      ushort4 o;
      o.x = f2bf(acc[r].x); o.y = f2bf(acc[r].y);
      o.z = f2bf(acc[r].z); o.w = f2bf(acc[r].w);
      *(ushort4*)&Tb[(size_t)gr * NF + cg * 4] = o;
    }
  }
}

// ---------------- aggregation (pull), bf16 gather ----------------
// one wave per node; 4 edge streams x 16 lanes; each lane owns 8 features (16B)

template <bool RELU, bool RES, bool BIAS, bool OUTBF>
__global__ __launch_bounds__(256) void agg128_kernel(const bfraw* __restrict__ Tb,
                                                     const int* __restrict__ rp,
                                                     const int2* __restrict__ ecsr,
                                                     const float* __restrict__ bias,
                                                     const float* __restrict__ Hres,
                                                     void* __restrict__ HoutV, int n) {
  int node = (blockIdx.x * 256 + threadIdx.x) >> 6;
  int lane = threadIdx.x & 63;
  if (node >= n) return;
  int st = lane >> 4;  // edge-stream 0..3
  int fl = lane & 15;  // features 8*fl .. 8*fl+7
  int beg = rp[node], end = rp[node + 1];
  float a[8];
  #pragma unroll
  for (int i = 0; i < 8; ++i) a[i] = 0.f;
  int eidx = beg + st;
  for (; eidx + 4 < end; eidx += 8) {
    int2 e0 = ecsr[eidx];
    int2 e1 = ecsr[eidx + 4];
    float w0 = __int_as_float(e0.y);
    float w1 = __int_as_float(e1.y);
    uint4 q0 = *(const uint4*)&Tb[(size_t)e0.x * NF + fl * 8];
    uint4 q1 = *(const uint4*)&Tb[(size_t)e1.x * NF + fl * 8];
    a[0] = fmaf(w0, bfLo(q0.x), a[0]); a[1] = fmaf(w0, bfHi(q0.x), a[1]);
    a[2] = fmaf(w0, bfLo(q0.y), a[2]); a[3] = fmaf(w0, bfHi(q0.y), a[3]);
    a[4] = fmaf(w0, bfLo(q0.z), a[4]); a[5] = fmaf(w0, bfHi(q0.z), a[5]);
    a[6] = fmaf(w0, bfLo(q0.w), a[6]); a[7] = fmaf(w0, bfHi(q0.w), a[7]);
    a[0] = fmaf(w1, bfLo(q1.x), a[0]); a[1] = fmaf(w1, bfHi(q1.x), a[1]);
    a[2] = fmaf(w1, bfLo(q1.y), a[2]); a[3] = fmaf(w1, bfHi(q1.y), a[3]);
    a[4] = fmaf(w1, bfLo(q1.z), a[4]); a[5] = fmaf(w1, bfHi(q1.z), a[5]);
    a[6] = fmaf(w1, bfLo(q1.w), a[6]); a[7] = fmaf(w1, bfHi(q1.w), a[7]);
  }
  if (eidx < end) {
    int2 e0 = ecsr[eidx];
    float w0 = __int_as_float(e0.y);
    uint4 q0 = *(const uint4*)&Tb[(size_t)e0.x * NF + fl * 8];
    a[0] = fmaf(w0, bfLo(q0.x), a[0]); a[1] = fmaf(w0, bfHi(q0.x), a[1]);
    a[2] = fmaf(w0, bfLo(q0.y), a[2]); a[3] = fmaf(w0, bfHi(q0.y), a[3]);
    a[4] = fmaf(w0, bfLo(q0.z), a[4]); a[5] = fmaf(w0, bfHi(q0.z), a[5]);
    a[6] = fmaf(w0, bfLo(q0.w), a[6]); a[7] = fmaf(w0, bfHi(q0.w), a[7]);
  }
  #pragma unroll
  for (int i = 0; i < 8; ++i) {
    a[i] += __shfl_xor(a[i], 16);
    a[i] += __shfl_xor(a[i], 32);
  }
  if (st == 0) {
    if (BIAS) {
      float4 b0 = *(const float4*)&bias[fl * 8];
      float4 b1 = *(const float4*)&bias[fl * 8 + 4];
      a[0] += b0.x; a[1] += b0.y; a[2] += b0.z; a[3] += b0.w;
      a[4] += b1.x; a[5] += b1.y; a[6] += b1.z; a[7] += b1.w;
    }
    if (RELU) {
      #pragma unroll
      for (int i = 0; i < 8; ++i) a[i] = fmaxf(a[i], 0.f);
    }
    if (RES) {
      float4 r0 = *(const float4*)&Hres[(size_t)node * NF + fl * 8];
      float4 r1 = *(const float4*)&Hres[(size_t)node * NF + fl * 8 + 4];
      a[0] += r0.x; a[1] += r0.y; a[2] += r0.z; a[3] += r0.w;
      a[4] += r1.x; a[5] += r1.y; a[6] += r1.z; a[7] += r1.w;
    }
    if (OUTBF) {
      bfraw* Hout = (bfraw*)HoutV;
      uint4 o;
      o.x = ((unsigned)f2bf(a[1]) << 16) | f2bf(a[0]);
      o.y = ((unsigned)f2bf(a[3]) << 16) | f2bf(a[2]);
      o.z = ((unsigned)f2bf(a[5]) << 16) | f2bf(a[4]);
      o.w = ((unsigned)f2bf(a[7]) << 16) | f2bf(a[6]);
      *(uint4*)&Hout[(size_t)node * NF + fl * 8] = o;
    } else {
      float* Hout = (float*)HoutV;
      float4 o0, o1;
      o0.x = a[0]; o0.y = a[1]; o0.z = a[2]; o0.w = a[3];
      o1.x = a[4]; o1.y = a[5]; o1.z = a[6]; o1.w = a[7];
      *(float4*)&Hout[(size_t)node * NF + fl * 8] = o0;
      *(float4*)&Hout[(size_t)node * NF + fl * 8 + 4] = o1;
    }
  }
}

// ---------------- fused final: out = log_softmax(A@W3 + b3) ----------------
// one thread per node: 40 accumulators; W3 staged in LDS, read as wave-uniform
// broadcast ds_read_b128; A row read as float4; softmax entirely in-thread.

__global__ __launch_bounds__(256) void gemm40_lsm_kernel(const float* __restrict__ A,
                                                         const float* __restrict__ W,
                                                         const float* __restrict__ bias,
                                                         float* __restrict__ out, int n) {
  __shared__ float Ws[NF * NC];  // 20 KB
  int tid = threadIdx.x;
  #pragma unroll
  for (int it = 0; it < 5; ++it) {
    int off = it * 1024 + tid * 4;
    *(float4*)&Ws[off] = *(const float4*)&W[off];
  }
  __syncthreads();
  int node = blockIdx.x * 256 + tid;
  if (node >= n) return;

  float4 acc[10];
  #pragma unroll
  for (int cg = 0; cg < 10; ++cg) acc[cg] = *(const float4*)&bias[cg * 4];

  const float* arow = A + (size_t)node * NF;
  for (int k0 = 0; k0 < NF; k0 += 4) {
    float4 a4 = *(const float4*)&arow[k0];
    float av[4] = {a4.x, a4.y, a4.z, a4.w};
    #pragma unroll
    for (int j = 0; j < 4; ++j) {
      #pragma unroll
      for (int cg = 0; cg < 10; ++cg) {
        float4 w4 = *(const float4*)&Ws[(k0 + j) * NC + cg * 4];
        acc[cg].x = fmaf(av[j], w4.x, acc[cg].x);
        acc[cg].y = fmaf(av[j], w4.y, acc[cg].y);
        acc[cg].z = fmaf(av[j], w4.z, acc[cg].z);
        acc[cg].w = fmaf(av[j], w4.w, acc[cg].w);
      }
    }
  }
  float m = -INFINITY;
  #pragma unroll
  for (int cg = 0; cg < 10; ++cg) {
    m = fmaxf(m, fmaxf(fmaxf(acc[cg].x, acc[cg].y), fmaxf(acc[cg].z, acc[cg].w)));
  }
  float s = 0.f;
  #pragma unroll
  for (int cg = 0; cg < 10; ++cg) {
    s += expf(acc[cg].x - m) + expf(acc[cg].y - m) +
         expf(acc[cg].z - m) + expf(acc[cg].w - m);
  }
  float lse = m + logf(s);
  float* orow = out + (size_t)node * NC;
  #pragma unroll
  for (int cg = 0; cg < 10; ++cg) {
    float4 o;
    o.x = acc[cg].x - lse; o.y = acc[cg].y - lse;
    o.z = acc[cg].z - lse; o.w = acc[cg].w - lse;
    *(float4*)&orow[cg * 4] = o;
  }
}

// ---------------- launch ----------------

extern "C" void kernel_launch(void* const* d_in, const int* in_sizes, int n_in,
                              void* d_out, int out_size, void* d_ws, size_t ws_size,
                              hipStream_t stream) {
  const float* x   = (const float*)d_in[0];
  const int*   src = (const int*)d_in[1];
  const int*   tgt = (const int*)d_in[2];
  const float* mw  = (const float*)d_in[3];
  const float* W0  = (const float*)d_in[4];
  const float* b0  = (const float*)d_in[5];
  const float* W1  = (const float*)d_in[6];
  const float* b1  = (const float*)d_in[7];
  const float* W2  = (const float*)d_in[8];
  const float* b2  = (const float*)d_in[9];
  const float* W3  = (const float*)d_in[10];
  const float* b3  = (const float*)d_in[11];
  int n = in_sizes[0] / NF;
  int e = in_sizes[1];
  float* out = (float*)d_out;

  char* ws = (char*)d_ws;
  size_t nbF = (size_t)n * NF * sizeof(float);                       // fp32 [N,128]
  size_t nbB = ((size_t)n * NF * sizeof(bfraw) + 255) / 256 * 256;   // bf16 [N,128]
  float* bufA = (float*)(ws);                 // h0 / A
  float* bufB = (float*)(ws + nbF);           // h1
  bfraw* bufT = (bfraw*)(ws + 2 * nbF);       // per-layer transform out (bf16)
  bfraw* bufC = (bfraw*)(ws + 2 * nbF + nbB); // h2 (bf16)
  char* p = ws + 2 * nbF + 2 * nbB;
  int* rp = (int*)p;     p += (((size_t)(n + 1) * 4) + 255) / 256 * 256;
  int* fill = (int*)p;   p += (((size_t)n * 4) + 255) / 256 * 256;
  int* bsum = (int*)p;   p += 4096;
  int2* ecsr = (int2*)p;

  hipMemsetAsync(fill, 0, (size_t)n * 4, stream);
  int eb = (e + 255) / 256;
  int nb1 = (n + 1023) / 1024;
  count_kernel<<<eb, 256, 0, stream>>>(tgt, fill, e);
  scan1_kernel<<<nb1, 1024, 0, stream>>>(fill, rp, bsum, n);
  scan2_kernel<<<1, 1024, 0, stream>>>(bsum, nb1, &rp[n]);
  scan3_kernel<<<(n + 255) / 256, 256, 0, stream>>>(rp, fill, bsum, n);
  fill_kernel<<<eb, 256, 0, stream>>>(src, tgt, mw, fill, ecsr, e);

  int gb = (n + 63) / 64;
  int ab = (n + 3) / 4;
  // L0: h0 = relu(agg(x@W0) + b0)
  gemm128_kernel<<<gb, 256, 0, stream>>>(x, W0, bufT, n);
  agg128_kernel<true, false, true, false><<<ab, 256, 0, stream>>>(
      bufT, rp, ecsr, b0, nullptr, bufA, n);
  // L1: h1 = relu(agg(h0@W1) + b1) + h0
  gemm128_kernel<<<gb, 256, 0, stream>>>(bufA, W1, bufT, n);
  agg128_kernel<true, true, true, false><<<ab, 256, 0, stream>>>(
      bufT, rp, ecsr, b1, bufA, bufB, n);
  // L2: h2 = relu(agg(h1@W2) + b2) + h1   (stored bf16)
  gemm128_kernel<<<gb, 256, 0, stream>>>(bufB, W2, bufT, n);
  agg128_kernel<true, true, true, true><<<ab, 256, 0, stream>>>(
      bufT, rp, ecsr, b2, bufB, bufC, n);
  // Final: A = agg(h2) ; out = log_softmax(A@W3 + b3)
  agg128_kernel<false, false, false, false><<<ab, 256, 0, stream>>>(
      bufC, rp, ecsr, nullptr, nullptr, bufA, n);
  gemm40_lsm_kernel<<<(n + 255) / 256, 256, 0, stream>>>(bufA, W3, b3, out, n);
}

// Round 5
// 588.874 us; speedup vs baseline: 2.0557x; 1.0853x over previous
//
#include <hip/hip_runtime.h>
#include <hip/hip_fp16.h>
#include <math.h>

#define NF 128
#define NC 40

typedef unsigned short bfraw;

__device__ __forceinline__ float bfLo(unsigned u) {
  return __uint_as_float(u << 16);
}
__device__ __forceinline__ float bfHi(unsigned u) {
  return __uint_as_float(u & 0xffff0000u);
}
__device__ __forceinline__ unsigned short f2bf(float f) {
  unsigned u = __float_as_uint(f);
  u += 0x7fff + ((u >> 16) & 1);  // RNE
  return (unsigned short)(u >> 16);
}
// weight in [0,1): positive fp16, 15 bits (no sign)
__device__ __forceinline__ unsigned short f2h15(float f) {
  __half h = __float2half(f);
  __half_raw hr = static_cast<__half_raw>(h);
  return (unsigned short)(hr.x & 0x7FFF);
}
__device__ __forceinline__ float h15tof(unsigned rec) {
  __half_raw hr;
  hr.x = (unsigned short)(rec & 0x7FFF);
  __half h = static_cast<__half>(hr);
  return __half2float(h);  // v_cvt_f32_f16 (handles subnormals in HW)
}

// ---------------- CSR build ----------------

__global__ __launch_bounds__(256) void count_kernel(const int* __restrict__ tgt,
                                                    int* __restrict__ cnt, int e) {
  int i = blockIdx.x * 256 + threadIdx.x;
  if (i < e) atomicAdd(&cnt[tgt[i]], 1);
}

__global__ __launch_bounds__(1024) void scan1_kernel(const int* __restrict__ cnt,
                                                     int* __restrict__ rp,
                                                     int* __restrict__ bsum, int n) {
  __shared__ int wsum[16];
  int tid = threadIdx.x, lane = tid & 63, wid = tid >> 6;
  int i = blockIdx.x * 1024 + tid;
  int v = (i < n) ? cnt[i] : 0;
  int x = v;
  #pragma unroll
  for (int off = 1; off < 64; off <<= 1) {
    int t = __shfl_up(x, off);
    if (lane >= off) x += t;
  }
  if (lane == 63) wsum[wid] = x;
  __syncthreads();
  if (wid == 0) {
    int ws = (lane < 16) ? wsum[lane] : 0;
    int y = ws;
    #pragma unroll
    for (int off = 1; off < 16; off <<= 1) {
      int t = __shfl_up(y, off);
      if (lane >= off) y += t;
    }
    if (lane < 16) wsum[lane] = y - ws;
  }
  __syncthreads();
  int incl = x + wsum[wid];
  if (i < n) rp[i] = incl - v;
  if (tid == 1023) bsum[blockIdx.x] = incl;
}

__global__ __launch_bounds__(1024) void scan2_kernel(int* __restrict__ bsum, int nb,
                                                     int* __restrict__ rp_n) {
  __shared__ int wsum[16];
  int tid = threadIdx.x, lane = tid & 63, wid = tid >> 6;
  int v = (tid < nb) ? bsum[tid] : 0;
  int x = v;
  #pragma unroll
  for (int off = 1; off < 64; off <<= 1) {
    int t = __shfl_up(x, off);
    if (lane >= off) x += t;
  }
  if (lane == 63) wsum[wid] = x;
  __syncthreads();
  if (wid == 0) {
    int ws = (lane < 16) ? wsum[lane] : 0;
    int y = ws;
    #pragma unroll
    for (int off = 1; off < 16; off <<= 1) {
      int t = __shfl_up(y, off);
      if (lane >= off) y += t;
    }
    if (lane < 16) wsum[lane] = y - ws;
  }
  __syncthreads();
  int incl = x + wsum[wid];
  if (tid < nb) bsum[tid] = incl - v;
  if (tid == 1023) *rp_n = incl;
}

__global__ __launch_bounds__(256) void scan3_kernel(int* __restrict__ rp,
                                                    int* __restrict__ cursor,
                                                    const int* __restrict__ bsum, int n) {
  int i = blockIdx.x * 256 + threadIdx.x;
  if (i < n) {
    int v = rp[i] + bsum[i >> 10];
    rp[i] = v;
    cursor[i] = v;
  }
}

// XCD-partitioned scatter: partition = blockIdx.x & 7 (round-robin dispatch puts
// each partition-set on one XCD -> ecsr lines assemble in ONE L2 before
// write-back; perf heuristic only, correctness independent of mapping).
// Record: src<<15 | fp16(weight) (positive, 15 bits).
__global__ __launch_bounds__(256) void fill_kernel(const int* __restrict__ src,
                                                   const int* __restrict__ tgt,
                                                   const float* __restrict__ mw,
                                                   int* __restrict__ cursor,
                                                   unsigned* __restrict__ ecsr,
                                                   int e, int n) {
  int part = blockIdx.x & 7;
  int nset = gridDim.x >> 3;
  int lo = (int)(((long long)n * part) >> 3);
  int hi = (int)(((long long)n * (part + 1)) >> 3);
  int stride = nset * 256;
  for (int i = (blockIdx.x >> 3) * 256 + threadIdx.x; i < e; i += stride) {
    int t = tgt[i];
    if (t >= lo && t < hi) {
      int pos = atomicAdd(&cursor[t], 1);
      unsigned rec = ((unsigned)src[i] << 15) | f2h15(mw[i]);
      ecsr[pos] = rec;
    }
  }
}

// ---------------- GEMM: Tb[N,128](bf16) = X[N,128] @ W[128,128] ----------------

__global__ __launch_bounds__(256) void gemm128_kernel(const float* __restrict__ X,
                                                      const float* __restrict__ W,
                                                      bfraw* __restrict__ Tb, int n) {
  __shared__ float Xs[64][NF];
  int block_row = blockIdx.x * 64;
  int tid = threadIdx.x;
  #pragma unroll
  for (int it = 0; it < 8; ++it) {
    int flat = it * 1024 + tid * 4;
    int r = flat >> 7, c = flat & 127;
    int gr = block_row + r;
    float4 v = make_float4(0.f, 0.f, 0.f, 0.f);
    if (gr < n) v = *(const float4*)&X[(size_t)gr * NF + c];
    *(float4*)&Xs[r][c] = v;
  }
  __syncthreads();
  int cg = tid & 31;
  int rg = tid >> 5;
  float4 acc[8];
  #pragma unroll
  for (int r = 0; r < 8; ++r) acc[r] = make_float4(0.f, 0.f, 0.f, 0.f);
  for (int k = 0; k < NF; ++k) {
    float4 w = *(const float4*)&W[k * NF + cg * 4];
    #pragma unroll
    for (int r = 0; r < 8; ++r) {
      float xv = Xs[rg * 8 + r][k];
      acc[r].x += xv * w.x;
      acc[r].y += xv * w.y;
      acc[r].z += xv * w.z;
      acc[r].w += xv * w.w;
    }
  }
  #pragma unroll
  for (int r = 0; r < 8; ++r) {
    int gr = block_row + rg * 8 + r;
    if (gr < n) {
      ushort4 o;
      o.x = f2bf(acc[r].x); o.y = f2bf(acc[r].y);
      o.z = f2bf(acc[r].z); o.w = f2bf(acc[r].w);
      *(ushort4*)&Tb[(size_t)gr * NF + cg * 4] = o;
    }
  }
}

// ---------------- aggregation (pull), bf16 gather ----------------
// one wave per node; 4 edge streams x 16 lanes; each lane owns 8 features (16B)

template <bool RELU, bool RES, bool BIAS, bool OUTBF>
__global__ __launch_bounds__(256) void agg128_kernel(const bfraw* __restrict__ Tb,
                                                     const int* __restrict__ rp,
                                                     const unsigned* __restrict__ ecsr,
                                                     const float* __restrict__ bias,
                                                     const float* __restrict__ Hres,
                                                     void* __restrict__ HoutV, int n) {
  int node = (blockIdx.x * 256 + threadIdx.x) >> 6;
  int lane = threadIdx.x & 63;
  if (node >= n) return;
  int st = lane >> 4;  // edge-stream 0..3
  int fl = lane & 15;  // features 8*fl .. 8*fl+7
  int beg = rp[node], end = rp[node + 1];
  float a[8];
  #pragma unroll
  for (int i = 0; i < 8; ++i) a[i] = 0.f;
  int eidx = beg + st;
  for (; eidx + 4 < end; eidx += 8) {
    unsigned e0 = ecsr[eidx];
    unsigned e1 = ecsr[eidx + 4];
    float w0 = h15tof(e0);
    float w1 = h15tof(e1);
    uint4 q0 = *(const uint4*)&Tb[(size_t)(e0 >> 15) * NF + fl * 8];
    uint4 q1 = *(const uint4*)&Tb[(size_t)(e1 >> 15) * NF + fl * 8];
    a[0] = fmaf(w0, bfLo(q0.x), a[0]); a[1] = fmaf(w0, bfHi(q0.x), a[1]);
    a[2] = fmaf(w0, bfLo(q0.y), a[2]); a[3] = fmaf(w0, bfHi(q0.y), a[3]);
    a[4] = fmaf(w0, bfLo(q0.z), a[4]); a[5] = fmaf(w0, bfHi(q0.z), a[5]);
    a[6] = fmaf(w0, bfLo(q0.w), a[6]); a[7] = fmaf(w0, bfHi(q0.w), a[7]);
    a[0] = fmaf(w1, bfLo(q1.x), a[0]); a[1] = fmaf(w1, bfHi(q1.x), a[1]);
    a[2] = fmaf(w1, bfLo(q1.y), a[2]); a[3] = fmaf(w1, bfHi(q1.y), a[3]);
    a[4] = fmaf(w1, bfLo(q1.z), a[4]); a[5] = fmaf(w1, bfHi(q1.z), a[5]);
    a[6] = fmaf(w1, bfLo(q1.w), a[6]); a[7] = fmaf(w1, bfHi(q1.w), a[7]);
  }
  if (eidx < end) {
    unsigned e0 = ecsr[eidx];
    float w0 = h15tof(e0);
    uint4 q0 = *(const uint4*)&Tb[(size_t)(e0 >> 15) * NF + fl * 8];
    a[0] = fmaf(w0, bfLo(q0.x), a[0]); a[1] = fmaf(w0, bfHi(q0.x), a[1]);
    a[2] = fmaf(w0, bfLo(q0.y), a[2]); a[3] = fmaf(w0, bfHi(q0.y), a[3]);
    a[4] = fmaf(w0, bfLo(q0.z), a[4]); a[5] = fmaf(w0, bfHi(q0.z), a[5]);
    a[6] = fmaf(w0, bfLo(q0.w), a[6]); a[7] = fmaf(w0, bfHi(q0.w), a[7]);
  }
  #pragma unroll
  for (int i = 0; i < 8; ++i) {
    a[i] += __shfl_xor(a[i], 16);
    a[i] += __shfl_xor(a[i], 32);
  }
  if (st == 0) {
    if (BIAS) {
      float4 b0 = *(const float4*)&bias[fl * 8];
      float4 b1 = *(const float4*)&bias[fl * 8 + 4];
      a[0] += b0.x; a[1] += b0.y; a[2] += b0.z; a[3] += b0.w;
      a[4] += b1.x; a[5] += b1.y; a[6] += b1.z; a[7] += b1.w;
    }
    if (RELU) {
      #pragma unroll
      for (int i = 0; i < 8; ++i) a[i] = fmaxf(a[i], 0.f);
    }
    if (RES) {
      float4 r0 = *(const float4*)&Hres[(size_t)node * NF + fl * 8];
      float4 r1 = *(const float4*)&Hres[(size_t)node * NF + fl * 8 + 4];
      a[0] += r0.x; a[1] += r0.y; a[2] += r0.z; a[3] += r0.w;
      a[4] += r1.x; a[5] += r1.y; a[6] += r1.z; a[7] += r1.w;
    }
    if (OUTBF) {
      bfraw* Hout = (bfraw*)HoutV;
      uint4 o;
      o.x = ((unsigned)f2bf(a[1]) << 16) | f2bf(a[0]);
      o.y = ((unsigned)f2bf(a[3]) << 16) | f2bf(a[2]);
      o.z = ((unsigned)f2bf(a[5]) << 16) | f2bf(a[4]);
      o.w = ((unsigned)f2bf(a[7]) << 16) | f2bf(a[6]);
      *(uint4*)&Hout[(size_t)node * NF + fl * 8] = o;
    } else {
      float* Hout = (float*)HoutV;
      float4 o0, o1;
      o0.x = a[0]; o0.y = a[1]; o0.z = a[2]; o0.w = a[3];
      o1.x = a[4]; o1.y = a[5]; o1.z = a[6]; o1.w = a[7];
      *(float4*)&Hout[(size_t)node * NF + fl * 8] = o0;
      *(float4*)&Hout[(size_t)node * NF + fl * 8 + 4] = o1;
    }
  }
}

// ---------------- fused final: out = log_softmax(A@W3 + b3) ----------------

__global__ __launch_bounds__(256) void gemm40_lsm_kernel(const float* __restrict__ A,
                                                         const float* __restrict__ W,
                                                         const float* __restrict__ bias,
                                                         float* __restrict__ out, int n) {
  __shared__ float Ws[NF * NC];  // 20 KB
  int tid = threadIdx.x;
  #pragma unroll
  for (int it = 0; it < 5; ++it) {
    int off = it * 1024 + tid * 4;
    *(float4*)&Ws[off] = *(const float4*)&W[off];
  }
  __syncthreads();
  int node = blockIdx.x * 256 + tid;
  if (node >= n) return;

  float4 acc[10];
  #pragma unroll
  for (int cg = 0; cg < 10; ++cg) acc[cg] = *(const float4*)&bias[cg * 4];

  const float* arow = A + (size_t)node * NF;
  for (int k0 = 0; k0 < NF; k0 += 4) {
    float4 a4 = *(const float4*)&arow[k0];
    float av[4] = {a4.x, a4.y, a4.z, a4.w};
    #pragma unroll
    for (int j = 0; j < 4; ++j) {
      #pragma unroll
      for (int cg = 0; cg < 10; ++cg) {
        float4 w4 = *(const float4*)&Ws[(k0 + j) * NC + cg * 4];
        acc[cg].x = fmaf(av[j], w4.x, acc[cg].x);
        acc[cg].y = fmaf(av[j], w4.y, acc[cg].y);
        acc[cg].z = fmaf(av[j], w4.z, acc[cg].z);
        acc[cg].w = fmaf(av[j], w4.w, acc[cg].w);
      }
    }
  }
  float m = -INFINITY;
  #pragma unroll
  for (int cg = 0; cg < 10; ++cg) {
    m = fmaxf(m, fmaxf(fmaxf(acc[cg].x, acc[cg].y), fmaxf(acc[cg].z, acc[cg].w)));
  }
  float s = 0.f;
  #pragma unroll
  for (int cg = 0; cg < 10; ++cg) {
    s += expf(acc[cg].x - m) + expf(acc[cg].y - m) +
         expf(acc[cg].z - m) + expf(acc[cg].w - m);
  }
  float lse = m + logf(s);
  float* orow = out + (size_t)node * NC;
  #pragma unroll
  for (int cg = 0; cg < 10; ++cg) {
    float4 o;
    o.x = acc[cg].x - lse; o.y = acc[cg].y - lse;
    o.z = acc[cg].z - lse; o.w = acc[cg].w - lse;
    *(float4*)&orow[cg * 4] = o;
  }
}

// ---------------- launch ----------------

extern "C" void kernel_launch(void* const* d_in, const int* in_sizes, int n_in,
                              void* d_out, int out_size, void* d_ws, size_t ws_size,
                              hipStream_t stream) {
  const float* x   = (const float*)d_in[0];
  const int*   src = (const int*)d_in[1];
  const int*   tgt = (const int*)d_in[2];
  const float* mw  = (const float*)d_in[3];
  const float* W0  = (const float*)d_in[4];
  const float* b0  = (const float*)d_in[5];
  const float* W1  = (const float*)d_in[6];
  const float* b1  = (const float*)d_in[7];
  const float* W2  = (const float*)d_in[8];
  const float* b2  = (const float*)d_in[9];
  const float* W3  = (const float*)d_in[10];
  const float* b3  = (const float*)d_in[11];
  int n = in_sizes[0] / NF;
  int e = in_sizes[1];
  float* out = (float*)d_out;

  char* ws = (char*)d_ws;
  size_t nbF = (size_t)n * NF * sizeof(float);                       // fp32 [N,128]
  size_t nbB = ((size_t)n * NF * sizeof(bfraw) + 255) / 256 * 256;   // bf16 [N,128]
  float* bufA = (float*)(ws);                 // h0 / A
  float* bufB = (float*)(ws + nbF);           // h1
  bfraw* bufT = (bfraw*)(ws + 2 * nbF);       // per-layer transform out (bf16)
  bfraw* bufC = (bfraw*)(ws + 2 * nbF + nbB); // h2 (bf16)
  char* p = ws + 2 * nbF + 2 * nbB;
  int* rp = (int*)p;     p += (((size_t)(n + 1) * 4) + 255) / 256 * 256;
  int* fill = (int*)p;   p += (((size_t)n * 4) + 255) / 256 * 256;
  int* bsum = (int*)p;   p += 4096;
  unsigned* ecsr = (unsigned*)p;

  hipMemsetAsync(fill, 0, (size_t)n * 4, stream);
  int eb = (e + 255) / 256;
  int nb1 = (n + 1023) / 1024;
  count_kernel<<<eb, 256, 0, stream>>>(tgt, fill, e);
  scan1_kernel<<<nb1, 1024, 0, stream>>>(fill, rp, bsum, n);
  scan2_kernel<<<1, 1024, 0, stream>>>(bsum, nb1, &rp[n]);
  scan3_kernel<<<(n + 255) / 256, 256, 0, stream>>>(rp, fill, bsum, n);
  fill_kernel<<<8 * 256, 256, 0, stream>>>(src, tgt, mw, fill, ecsr, e, n);

  int gb = (n + 63) / 64;
  int ab = (n + 3) / 4;
  // L0: h0 = relu(agg(x@W0) + b0)
  gemm128_kernel<<<gb, 256, 0, stream>>>(x, W0, bufT, n);
  agg128_kernel<true, false, true, false><<<ab, 256, 0, stream>>>(
      bufT, rp, ecsr, b0, nullptr, bufA, n);
  // L1: h1 = relu(agg(h0@W1) + b1) + h0
  gemm128_kernel<<<gb, 256, 0, stream>>>(bufA, W1, bufT, n);
  agg128_kernel<true, true, true, false><<<ab, 256, 0, stream>>>(
      bufT, rp, ecsr, b1, bufA, bufB, n);
  // L2: h2 = relu(agg(h1@W2) + b2) + h1   (stored bf16)
  gemm128_kernel<<<gb, 256, 0, stream>>>(bufB, W2, bufT, n);
  agg128_kernel<true, true, true, true><<<ab, 256, 0, stream>>>(
      bufT, rp, ecsr, b2, bufB, bufC, n);
  // Final: A = agg(h2) ; out = log_softmax(A@W3 + b3)
  agg128_kernel<false, false, false, false><<<ab, 256, 0, stream>>>(
      bufC, rp, ecsr, nullptr, nullptr, bufA, n);
  gemm40_lsm_kernel<<<(n + 255) / 256, 256, 0, stream>>>(bufA, W3, b3, out, n);
}